// Round 8
// baseline (429.632 us; speedup 1.0000x reference)
//
#include <hip/hip_runtime.h>

#define B 8
#define N 1024
#define M 128
#define KF 16
#define C 16
#define DPE 64
#define NE 131072
#define NV (B*N)
#define NM (N*M)
#define BN_EPS 1e-5f

typedef short bf16x8 __attribute__((ext_vector_type(8)));
typedef float f32x4 __attribute__((ext_vector_type(4)));

__device__ inline unsigned short f2bf_rne(float f) {
    unsigned u = __float_as_uint(f);
    u += 0x7fffu + ((u >> 16) & 1u);
    return (unsigned short)(u >> 16);
}
__device__ inline float bf2f(unsigned short s) {
    return __uint_as_float((unsigned)s << 16);
}
__device__ inline void split_bf16(float v, unsigned short& hi, unsigned short& lo) {
    hi = f2bf_rne(v);
    float hf = __uint_as_float((unsigned)hi << 16);
    lo = f2bf_rne(v - hf);
}
union U4 { uint4 v; unsigned short s[8]; };
union U2 { uint2 v; unsigned short s[4]; };

// Pf frag-major (uint4 units) per buffer: PF4(b,msub,ks,hl,l)
// frag el: m = 16*msub + (l&15), kcol = 32*ks + 8*(l>>4) + j
__device__ __host__ inline size_t PF4(int b, int msub, int ks, int hl, int l) {
    return ((((size_t)b * 8 + msub) * 32 + ks) * 2 + hl) * 64 + l;
}
#define PFBUF ((size_t)B * 8 * 32 * 2 * 64)   // uint4 per Pf buffer (4MB)

// ---------- fused prep: W plane0 | W-frags | edge histogram ----------
// (prep_s eliminated: gemm_chain loads S directly from Lap -- R23-validated)
__global__ __launch_bounds__(256) void prep_all(const float* __restrict__ W,
                                                const int* __restrict__ ei,
                                                uint4* __restrict__ Pf,
                                                unsigned short* __restrict__ feat,
                                                int* __restrict__ cnt) {
    __shared__ float T[32][33];
    int blk = blockIdx.x;
    int t = threadIdx.x;
    if (blk < 1024) {                         // ---- prep_w_plane (bf16) ----
        int r = blk;
        int b = r & 7;
        int tile = r >> 3;
        int nt = tile & 31, mt = tile >> 5;
        int n0 = nt * 32, m0 = mt * 32;
        {
            int nl = t >> 3, mq = t & 7;
            float4 v = *(const float4*)(W + ((size_t)b * N + n0 + nl) * M + m0 + mq * 4);
            T[nl][mq * 4 + 0] = v.x; T[nl][mq * 4 + 1] = v.y;
            T[nl][mq * 4 + 2] = v.z; T[nl][mq * 4 + 3] = v.w;
        }
        __syncthreads();
        {
            int ml = t >> 3, nq = t & 7;
            U2 o;
            o.s[0] = f2bf_rne(T[nq * 4 + 0][ml]);
            o.s[1] = f2bf_rne(T[nq * 4 + 1][ml]);
            o.s[2] = f2bf_rne(T[nq * 4 + 2][ml]);
            o.s[3] = f2bf_rne(T[nq * 4 + 3][ml]);
            unsigned short* plane = feat + (size_t)b * KF * NM;  // plane 0
            *(uint2*)(plane + (size_t)(m0 + ml) * N + n0 + nq * 4) = o.v;
        }
    } else if (blk < 1536) {                  // ---- prep_w_frag ----
        int r0 = blk - 1024;
        int b = r0 & 7;
        int r = (r0 >> 3) * 256 + t;
        int msub = r >> 11, ks = (r >> 6) & 31, l = r & 63;
        int m = 16 * msub + (l & 15);
        U4 hi, lo;
        #pragma unroll
        for (int j = 0; j < 8; j++) {
            int n = 32 * ks + 8 * (l >> 4) + j;
            float v = W[((size_t)b * N + n) * M + m];
            split_bf16(v, hi.s[j], lo.s[j]);
        }
        Pf[PF4(b, msub, ks, 0, l)] = hi.v;
        Pf[PF4(b, msub, ks, 1, l)] = lo.v;
    } else {                                  // ---- edge_hist ----
        int e = (blk - 1536) * 256 + t;
        bool is64 = (ei[1] == 0 && ei[3] == 0 && ei[5] == 0 && ei[7] == 0);
        int dst = is64 ? ei[2 * (NE + e)] : ei[NE + e];
        atomicAdd(&cnt[dst], 1);
    }
}

// ---------- persistent MFMA chain ----------
// R26 = R25 with the split-K reduction collapsed: Dl is pre-zeroed, BOTH
// K-half groups ds_add_f32 (__hip_atomic_fetch_add, workgroup scope) their
// acc into Dl concurrently -> one concurrent LDS pass instead of two
// serialized passes, and 3 syncs/step instead of 4. Dl re-zeroing for the
// next step is hidden under t0's barrier spin. Numerics bit-identical
// (float add commutes). No polling in the loop (R19/R21 lesson); topology
// pinned at 32 blocks/batch, split-K, t0-only spinner (R22/R23/R24).
__global__ __launch_bounds__(512) void gemm_chain(const float* __restrict__ Lap,
                                                  uint4* __restrict__ PfA,
                                                  uint4* __restrict__ PfB,
                                                  unsigned short* __restrict__ feat,
                                                  unsigned* bar) {
    extern __shared__ __align__(16) char smem[];
    uint4* ldsS = (uint4*)smem;               // 8192 uint4 = 128 KB
    float* Dl = (float*)(smem + 131072);      // 128 x 36 floats = 18.4 KB

    int b = blockIdx.x & 7, bx = blockIdx.x >> 3;   // XCD pinning
    int t = threadIdx.x;
    int w = t >> 6, lane = t & 63;
    int g = w >> 2, wq = w & 3;               // K-half, msub-pair
    int n0 = 32 * bx;

    // ---- startup: S slice (rows n0..n0+31, all k) direct from Lap -> LDS ----
    // layout: ldsS[nsubLocal*4096 + ks*128 + hl*64 + l], ks 0..31
    // frag el = S[n = 16*nsubLocal + (l&15) + n0][k = 32*ks + 8*(l>>4) + j]
    {
        int nl = t >> 4;                      // 0..31 (row within slice)
        int kg = t & 15;
        const float* row = Lap + ((size_t)b * N + n0 + nl) * N;
        int base = (nl >> 4) * 4096;
        #pragma unroll
        for (int jj = 0; jj < 8; jj++) {
            int koct = kg + 16 * jj;
            int k0 = koct * 8;
            float4 f0 = *(const float4*)(row + k0);
            float4 f1 = *(const float4*)(row + k0 + 4);
            float e[8] = {f0.x, f0.y, f0.z, f0.w, f1.x, f1.y, f1.z, f1.w};
            U4 hi, lo;
            #pragma unroll
            for (int j = 0; j < 8; j++) split_bf16(e[j], hi.s[j], lo.s[j]);
            int ks = koct >> 2;
            int l = (nl & 15) + 16 * (koct & 3);
            ldsS[base + ks * 128 + l] = hi.v;
            ldsS[base + ks * 128 + 64 + l] = lo.v;
        }
    }
    // zero Dl for step 0's atomic reduction (4608 = 512 x 9)
    #pragma unroll
    for (int j = 0; j < 9; j++) Dl[t + 512 * j] = 0.0f;
    __syncthreads();

    #pragma unroll 1
    for (int k = 0; k < KF - 1; k++) {
        const uint4* PfIn = (k & 1) ? PfB : PfA;
        uint4* PfOut      = (k & 1) ? PfA : PfB;
        const uint4* Pw0 = PfIn + (size_t)(b * 8 + 2 * wq) * 4096 + (size_t)(16 * g) * 128;
        const uint4* Pw1 = Pw0 + 4096;

        f32x4 acc[2][2] = {};                 // [mi][ni]
        uint4 ph[2][2], pl[2][2];             // [ring][mi]
        #pragma unroll
        for (int q = 0; q < 2; q++) {
            ph[q][0] = Pw0[(size_t)q * 128 + lane];
            pl[q][0] = Pw0[(size_t)q * 128 + 64 + lane];
            ph[q][1] = Pw1[(size_t)q * 128 + lane];
            pl[q][1] = Pw1[(size_t)q * 128 + 64 + lane];
        }
        #pragma unroll 2
        for (int ks = 0; ks < 16; ks++) {
            int kg = 16 * g + ks;
            uint4 a0h = ph[ks & 1][0], a0l = pl[ks & 1][0];
            uint4 a1h = ph[ks & 1][1], a1l = pl[ks & 1][1];
            if (ks < 14) {
                ph[ks & 1][0] = Pw0[(size_t)(ks + 2) * 128 + lane];
                pl[ks & 1][0] = Pw0[(size_t)(ks + 2) * 128 + 64 + lane];
                ph[ks & 1][1] = Pw1[(size_t)(ks + 2) * 128 + lane];
                pl[ks & 1][1] = Pw1[(size_t)(ks + 2) * 128 + 64 + lane];
            }
            bf16x8 b0h = __builtin_bit_cast(bf16x8, ldsS[kg * 128 + lane]);
            bf16x8 b0l = __builtin_bit_cast(bf16x8, ldsS[kg * 128 + 64 + lane]);
            bf16x8 b1h = __builtin_bit_cast(bf16x8, ldsS[4096 + kg * 128 + lane]);
            bf16x8 b1l = __builtin_bit_cast(bf16x8, ldsS[4096 + kg * 128 + 64 + lane]);
            bf16x8 A0h = __builtin_bit_cast(bf16x8, a0h);
            bf16x8 A0l = __builtin_bit_cast(bf16x8, a0l);
            bf16x8 A1h = __builtin_bit_cast(bf16x8, a1h);
            bf16x8 A1l = __builtin_bit_cast(bf16x8, a1l);
            acc[0][0] = __builtin_amdgcn_mfma_f32_16x16x32_bf16(A0h, b0h, acc[0][0], 0, 0, 0);
            acc[0][0] = __builtin_amdgcn_mfma_f32_16x16x32_bf16(A0h, b0l, acc[0][0], 0, 0, 0);
            acc[0][0] = __builtin_amdgcn_mfma_f32_16x16x32_bf16(A0l, b0h, acc[0][0], 0, 0, 0);
            acc[0][1] = __builtin_amdgcn_mfma_f32_16x16x32_bf16(A0h, b1h, acc[0][1], 0, 0, 0);
            acc[0][1] = __builtin_amdgcn_mfma_f32_16x16x32_bf16(A0h, b1l, acc[0][1], 0, 0, 0);
            acc[0][1] = __builtin_amdgcn_mfma_f32_16x16x32_bf16(A0l, b1h, acc[0][1], 0, 0, 0);
            acc[1][0] = __builtin_amdgcn_mfma_f32_16x16x32_bf16(A1h, b0h, acc[1][0], 0, 0, 0);
            acc[1][0] = __builtin_amdgcn_mfma_f32_16x16x32_bf16(A1h, b0l, acc[1][0], 0, 0, 0);
            acc[1][0] = __builtin_amdgcn_mfma_f32_16x16x32_bf16(A1l, b0h, acc[1][0], 0, 0, 0);
            acc[1][1] = __builtin_amdgcn_mfma_f32_16x16x32_bf16(A1h, b1h, acc[1][1], 0, 0, 0);
            acc[1][1] = __builtin_amdgcn_mfma_f32_16x16x32_bf16(A1h, b1l, acc[1][1], 0, 0, 0);
            acc[1][1] = __builtin_amdgcn_mfma_f32_16x16x32_bf16(A1l, b1h, acc[1][1], 0, 0, 0);
        }

        // ---- split-K reduction: BOTH groups ds_add_f32 into zeroed Dl ----
        // (concurrent, order-free; float add commutes -> bit-identical)
        #pragma unroll
        for (int mi = 0; mi < 2; mi++)
            #pragma unroll
            for (int ni = 0; ni < 2; ni++)
                #pragma unroll
                for (int r = 0; r < 4; r++) {
                    int m = 32 * wq + 16 * mi + 4 * (lane >> 4) + r;
                    int c = 16 * ni + (lane & 15);
                    (void)__hip_atomic_fetch_add(&Dl[m * 36 + c], acc[mi][ni][r],
                                                 __ATOMIC_RELAXED,
                                                 __HIP_MEMORY_SCOPE_WORKGROUP);
                }
        __syncthreads();                      // sync_a: all adds landed

        // ---- merged conversion: ONE split pass -> feat plane + Pf frags ----
        {
            int m = t >> 2, c0 = (t & 3) * 8;   // thread covers (m, c0..c0+7)
            float4 v0 = *(const float4*)&Dl[m * 36 + c0];
            float4 v1 = *(const float4*)&Dl[m * 36 + c0 + 4];
            float e[8] = {v0.x, v0.y, v0.z, v0.w, v1.x, v1.y, v1.z, v1.w};
            U4 hi, lo;
            #pragma unroll
            for (int j = 0; j < 8; j++) split_bf16(e[j], hi.s[j], lo.s[j]);
            unsigned short* plane = feat + ((size_t)b * KF + (k + 1)) * NM
                                        + (size_t)m * N + n0 + c0;
            *(uint4*)plane = hi.v;
            if (k < KF - 2) {
                int l = (m & 15) + 16 * (c0 >> 3);    // bijection onto 0..63/wave
                PfOut[PF4(b, m >> 4, bx, 0, l)] = hi.v;
                PfOut[PF4(b, m >> 4, bx, 1, l)] = lo.v;
            }
        }
        if (k < KF - 2) {
            __syncthreads();   // sync_b: conversion reads done + stores drained (vmcnt 0)
            if (t == 0)
                __hip_atomic_fetch_add(&bar[b * 32], 1u, __ATOMIC_RELAXED,
                                       __HIP_MEMORY_SCOPE_AGENT);
            // re-zero Dl for the next step -- hidden under t0's spin
            #pragma unroll
            for (int j = 0; j < 9; j++) Dl[t + 512 * j] = 0.0f;
            if (t == 0) {
                unsigned target = 32u * (unsigned)(k + 1);
                while (__hip_atomic_load(&bar[b * 32], __ATOMIC_RELAXED,
                                         __HIP_MEMORY_SCOPE_AGENT) < target)
                    __builtin_amdgcn_s_sleep(1);
            }
            __syncthreads();   // sync_c: zeroing done + barrier passed
            // invalidate this CU's vector L1 so Pf reads come from fresh L2
            asm volatile("buffer_inv sc0\n\ts_waitcnt vmcnt(0)" ::: "memory");
        }
    }
}

// ---------- BN stats (XCD-aligned, bf16 feat) + edge CSR scan (block 0) ----------
__global__ __launch_bounds__(256) void bn_stats_scan(const unsigned short* __restrict__ feat,
                                                     const float* __restrict__ lin_w,
                                                     const float* __restrict__ lin_b,
                                                     float* __restrict__ stats,
                                                     const int* __restrict__ cnt,
                                                     int* __restrict__ off,
                                                     int* __restrict__ cur) {
    __shared__ float wls[KF * C];
    __shared__ float red[4][2][C];
    __shared__ int ss[256];
    int t = threadIdx.x;
    if (blockIdx.x < 8) {                 // ---- edge_scan (block 0 only) ----
        if (blockIdx.x == 0) {
            int base = t * 32;
            int local[32];
            int s = 0;
            #pragma unroll
            for (int i = 0; i < 32; i++) { local[i] = cnt[base + i]; s += local[i]; }
            ss[t] = s;
            __syncthreads();
            #pragma unroll
            for (int d = 1; d < 256; d <<= 1) {
                int v = (t >= d) ? ss[t - d] : 0;
                __syncthreads();
                ss[t] += v;
                __syncthreads();
            }
            int excl = ss[t] - s;
            #pragma unroll
            for (int i = 0; i < 32; i++) { off[base + i] = excl; cur[base + i] = excl; excl += local[i]; }
        }
        return;
    }
    int blk = blockIdx.x - 8;             // ---- bn_stats ----
    wls[t] = lin_w[t];
    __syncthreads();
    int b = blk & 7;
    int i = (blk >> 3) * 256 + t;          // group of 4 elems, 32768/batch
    const uint2* fb = (const uint2*)(feat + (size_t)b * KF * NM);

    float4 hacc[C];
    #pragma unroll
    for (int c = 0; c < C; c++) {
        float bb = lin_b[c];
        hacc[c] = make_float4(bb, bb, bb, bb);
    }
    for (int kk = 0; kk < KF; kk++) {
        U2 u; u.v = fb[(size_t)kk * (NM / 4) + i];
        float p0 = bf2f(u.s[0]), p1 = bf2f(u.s[1]), p2 = bf2f(u.s[2]), p3 = bf2f(u.s[3]);
        #pragma unroll
        for (int c = 0; c < C; c++) {
            float wv = wls[kk * C + c];
            hacc[c].x = fmaf(p0, wv, hacc[c].x);
            hacc[c].y = fmaf(p1, wv, hacc[c].y);
            hacc[c].z = fmaf(p2, wv, hacc[c].z);
            hacc[c].w = fmaf(p3, wv, hacc[c].w);
        }
    }
    float s[C], ssq[C];
    #pragma unroll
    for (int c = 0; c < C; c++) {
        float4 hh = hacc[c];
        s[c] = hh.x + hh.y + hh.z + hh.w;
        ssq[c] = hh.x * hh.x + hh.y * hh.y + hh.z * hh.z + hh.w * hh.w;
    }
    #pragma unroll
    for (int o = 32; o > 0; o >>= 1)
        #pragma unroll
        for (int c = 0; c < C; c++) {
            s[c] += __shfl_down(s[c], o);
            ssq[c] += __shfl_down(ssq[c], o);
        }
    if ((t & 63) == 0) {
        int wv = t >> 6;
        #pragma unroll
        for (int c = 0; c < C; c++) { red[wv][0][c] = s[c]; red[wv][1][c] = ssq[c]; }
    }
    __syncthreads();
    if (t < 32) {
        int which = t >> 4, c = t & 15;
        float v = red[0][which][c] + red[1][which][c] + red[2][which][c] + red[3][which][c];
        atomicAdd(&stats[b * 32 + which * 16 + c], v);
    }
}

// ---------- BN apply + relu + mean over M -> x | edge fill (blocks >= 256) ----------
__global__ __launch_bounds__(256) void bnx_fill(const unsigned short* __restrict__ feat,
                                                const float* __restrict__ lin_w,
                                                const float* __restrict__ lin_b,
                                                const float* __restrict__ gam,
                                                const float* __restrict__ bet,
                                                const float* __restrict__ stats,
                                                float* __restrict__ x,
                                                const int* __restrict__ ei,
                                                int* __restrict__ cur,
                                                int* __restrict__ bucket) {
    __shared__ float wls[KF * C];
    __shared__ float red[8][32 * 17];
    int t = threadIdx.x;
    if (blockIdx.x >= 256) {              // ---- edge_fill ----
        int e = (blockIdx.x - 256) * 256 + t;
        bool is64 = (ei[1] == 0 && ei[3] == 0 && ei[5] == 0 && ei[7] == 0);
        int src, dst;
        if (is64) { src = ei[2 * e]; dst = ei[2 * (NE + e)]; }
        else      { src = ei[e];     dst = ei[NE + e]; }
        int pos = atomicAdd(&cur[dst], 1);
        bucket[pos] = src;
        return;
    }
    // ---- bn_x ----
    wls[t] = lin_w[t];
    __syncthreads();
    int grp = blockIdx.x;
    int b = grp & 7, n0 = (grp >> 3) * 32;
    int nl = t & 31, mg = t >> 5;
    int n = n0 + nl;

    const float inv_nm = 1.0f / (float)NM;
    float sc[C], sh[C], bb[C];
    #pragma unroll
    for (int c = 0; c < C; c++) {
        float mean = stats[b * 32 + c] * inv_nm;
        float var = stats[b * 32 + 16 + c] * inv_nm - mean * mean;
        sc[c] = gam[c] * rsqrtf(var + BN_EPS);
        sh[c] = bet[c] - mean * sc[c];
        bb[c] = lin_b[c];
    }
    const unsigned short* fb = feat + (size_t)b * KF * NM + n;
    float y[C] = {};
    for (int m = mg * 16; m < mg * 16 + 16; m++) {
        float p[KF];
        #pragma unroll
        for (int kk = 0; kk < KF; kk++) p[kk] = bf2f(fb[(size_t)kk * NM + (size_t)m * N]);
        #pragma unroll
        for (int c = 0; c < C; c++) {
            float hh = bb[c];
            #pragma unroll
            for (int kk = 0; kk < KF; kk++) hh = fmaf(p[kk], wls[kk * C + c], hh);
            y[c] += fmaxf(fmaf(hh, sc[c], sh[c]), 0.0f);
        }
    }
    #pragma unroll
    for (int c = 0; c < C; c++) red[mg][nl * 17 + c] = y[c];
    __syncthreads();
    #pragma unroll
    for (int q = 0; q < 2; q++) {
        int slot = t + q * 256;
        int snl = slot >> 4, c = slot & 15;
        float v = 0.0f;
        #pragma unroll
        for (int m8 = 0; m8 < 8; m8++) v += red[m8][snl * 17 + c];
        v *= (1.0f / (float)M);
        x[((size_t)b * N + n0 + snl) * C + c] = v;
    }
}

// ---------- fused gather + phi1 + phi2 ----------
__global__ __launch_bounds__(256) void phi_fused(const int* __restrict__ cnt,
                                                 const int* __restrict__ off,
                                                 const int* __restrict__ bucket,
                                                 const float* __restrict__ x,
                                                 const float* __restrict__ w1,
                                                 const float* __restrict__ b1,
                                                 const float* __restrict__ w2,
                                                 const float* __restrict__ b2,
                                                 float* __restrict__ out) {
    __shared__ float w1s[C * DPE];
    __shared__ float w2s[DPE * DPE];
    __shared__ float b2s[DPE];
    __shared__ float gsh[16][17];
    __shared__ float h1sh[16][DPE];
    int t = threadIdx.x;
    #pragma unroll
    for (int q = 0; q < 4; q++) w1s[t + q * 256] = w1[t + q * 256];
    #pragma unroll
    for (int q = 0; q < 16; q++) w2s[t + q * 256] = w2[t + q * 256];
    if (t < DPE) b2s[t] = b2[t];

    {   // gather: node nl, channel c
        int nl = t >> 4, c = t & 15;
        int n = blockIdx.x * 16 + nl;
        int o = off[n], d = cnt[n];
        float v = x[(size_t)n * C + c];
        int j = 0;
        for (; j + 4 <= d; j += 4) {
            int s0 = bucket[o + j], s1 = bucket[o + j + 1];
            int s2 = bucket[o + j + 2], s3 = bucket[o + j + 3];
            v += x[(size_t)s0 * C + c];
            v += x[(size_t)s1 * C + c];
            v += x[(size_t)s2 * C + c];
            v += x[(size_t)s3 * C + c];
        }
        for (; j < d; j++) v += x[(size_t)bucket[o + j] * C + c];
        gsh[nl][c] = v;
    }
    __syncthreads();
    #pragma unroll
    for (int q = 0; q < 4; q++) {       // phi1: 16 nodes x 64
        int item = t + 256 * q;
        int node = item >> 6, j = item & 63;
        float h = b1[j];
        #pragma unroll
        for (int c = 0; c < C; c++) h = fmaf(gsh[node][c], w1s[c * DPE + j], h);
        h1sh[node][j] = fmaxf(h, 0.0f);
    }
    __syncthreads();
    #pragma unroll
    for (int q = 0; q < 4; q++) {       // phi2: 16 nodes x 64
        int item = t + 256 * q;
        int node = item >> 6, d = item & 63;
        float o2 = b2s[d];
        #pragma unroll
        for (int j = 0; j < DPE; j++) o2 = fmaf(h1sh[node][j], w2s[j * DPE + d], o2);
        out[((size_t)blockIdx.x * 16 + node) * DPE + d] = o2;
    }
}

extern "C" void kernel_launch(void* const* d_in, const int* in_sizes, int n_in,
                              void* d_out, int out_size, void* d_ws, size_t ws_size,
                              hipStream_t stream) {
    const float* Lap   = (const float*)d_in[0];
    const float* W     = (const float*)d_in[1];
    const float* lin_w = (const float*)d_in[2];
    const float* lin_b = (const float*)d_in[3];
    const float* gam   = (const float*)d_in[4];
    const float* bet   = (const float*)d_in[5];
    const float* w1    = (const float*)d_in[6];
    const float* b1    = (const float*)d_in[7];
    const float* w2    = (const float*)d_in[8];
    const float* b2    = (const float*)d_in[9];
    const int*   ei    = (const int*)d_in[10];

    char* wsb = (char*)d_ws;
    unsigned short* feat = (unsigned short*)wsb;             // 32 MB (bf16)
    uint4* Pf    = (uint4*)(wsb + ((size_t)32 << 20));       // 8 MB (2 buffers)
    char* tail   = wsb + ((size_t)40 << 20);
    float* stats = (float*)tail;                             // 1 KB
    unsigned* bar = (unsigned*)(tail + 1024);                // 8 counters, 128B apart
    int* cnt     = (int*)(tail + 8192);                      // NV ints (32 KB)
    float* x     = (float*)(tail + 40960);
    int* off     = (int*)(x + (size_t)NV * C);
    int* cur     = off + NV;
    int* bucket  = cur + NV;                                 // NE ints
    float* out   = (float*)d_out;

    // allow 146 KB dynamic LDS (default cap is 64 KB); idempotent host-side call
    static bool attr_set = false;
    if (!attr_set) {
        hipFuncSetAttribute((const void*)gemm_chain,
                            hipFuncAttributeMaxDynamicSharedMemorySize, 149504);
        attr_set = true;
    }

    // one memset covers stats + bar + cnt (contiguous 40 KB)
    hipMemsetAsync(tail, 0, 40960, stream);
    prep_all<<<dim3(2048), 256, 0, stream>>>(W, ei, Pf, feat, cnt);
    gemm_chain<<<dim3(256), 512, 149504, stream>>>(Lap, Pf, Pf + PFBUF, feat, bar);
    bn_stats_scan<<<dim3(1032), 256, 0, stream>>>(feat, lin_w, lin_b, stats, cnt, off, cur);
    bnx_fill<<<dim3(768), 256, 0, stream>>>(feat, lin_w, lin_b, gam, bet, stats, x, ei, cur, bucket);
    phi_fused<<<dim3(NV / 16), 256, 0, stream>>>(cnt, off, bucket, x, w1, b1, w2, b2, out);
}

// Round 9
// 281.791 us; speedup vs baseline: 1.5246x; 1.5246x over previous
//
#include <hip/hip_runtime.h>

#define B 8
#define N 1024
#define M 128
#define KF 16
#define C 16
#define DPE 64
#define NE 131072
#define NV (B*N)
#define NM (N*M)
#define BN_EPS 1e-5f

typedef short bf16x8 __attribute__((ext_vector_type(8)));
typedef float f32x4 __attribute__((ext_vector_type(4)));

__device__ inline unsigned short f2bf_rne(float f) {
    unsigned u = __float_as_uint(f);
    u += 0x7fffu + ((u >> 16) & 1u);
    return (unsigned short)(u >> 16);
}
__device__ inline float bf2f(unsigned short s) {
    return __uint_as_float((unsigned)s << 16);
}
__device__ inline void split_bf16(float v, unsigned short& hi, unsigned short& lo) {
    hi = f2bf_rne(v);
    float hf = __uint_as_float((unsigned)hi << 16);
    lo = f2bf_rne(v - hf);
}
union U4 { uint4 v; unsigned short s[8]; };
union U2 { uint2 v; unsigned short s[4]; };

// Pf frag-major (uint4 units) per buffer: PF4(b,msub,ks,hl,l)
// frag el: m = 16*msub + (l&15), kcol = 32*ks + 8*(l>>4) + j
__device__ __host__ inline size_t PF4(int b, int msub, int ks, int hl, int l) {
    return ((((size_t)b * 8 + msub) * 32 + ks) * 2 + hl) * 64 + l;
}
#define PFBUF ((size_t)B * 8 * 32 * 2 * 64)   // uint4 per Pf buffer (4MB)

// ---------- fused prep: W plane0 | W-frags | edge histogram ----------
// (prep_s eliminated: gemm_chain loads S directly from Lap -- R23-validated)
__global__ __launch_bounds__(256) void prep_all(const float* __restrict__ W,
                                                const int* __restrict__ ei,
                                                uint4* __restrict__ Pf,
                                                unsigned short* __restrict__ feat,
                                                int* __restrict__ cnt) {
    __shared__ float T[32][33];
    int blk = blockIdx.x;
    int t = threadIdx.x;
    if (blk < 1024) {                         // ---- prep_w_plane (bf16) ----
        int r = blk;
        int b = r & 7;
        int tile = r >> 3;
        int nt = tile & 31, mt = tile >> 5;
        int n0 = nt * 32, m0 = mt * 32;
        {
            int nl = t >> 3, mq = t & 7;
            float4 v = *(const float4*)(W + ((size_t)b * N + n0 + nl) * M + m0 + mq * 4);
            T[nl][mq * 4 + 0] = v.x; T[nl][mq * 4 + 1] = v.y;
            T[nl][mq * 4 + 2] = v.z; T[nl][mq * 4 + 3] = v.w;
        }
        __syncthreads();
        {
            int ml = t >> 3, nq = t & 7;
            U2 o;
            o.s[0] = f2bf_rne(T[nq * 4 + 0][ml]);
            o.s[1] = f2bf_rne(T[nq * 4 + 1][ml]);
            o.s[2] = f2bf_rne(T[nq * 4 + 2][ml]);
            o.s[3] = f2bf_rne(T[nq * 4 + 3][ml]);
            unsigned short* plane = feat + (size_t)b * KF * NM;  // plane 0
            *(uint2*)(plane + (size_t)(m0 + ml) * N + n0 + nq * 4) = o.v;
        }
    } else if (blk < 1536) {                  // ---- prep_w_frag ----
        int r0 = blk - 1024;
        int b = r0 & 7;
        int r = (r0 >> 3) * 256 + t;
        int msub = r >> 11, ks = (r >> 6) & 31, l = r & 63;
        int m = 16 * msub + (l & 15);
        U4 hi, lo;
        #pragma unroll
        for (int j = 0; j < 8; j++) {
            int n = 32 * ks + 8 * (l >> 4) + j;
            float v = W[((size_t)b * N + n) * M + m];
            split_bf16(v, hi.s[j], lo.s[j]);
        }
        Pf[PF4(b, msub, ks, 0, l)] = hi.v;
        Pf[PF4(b, msub, ks, 1, l)] = lo.v;
    } else {                                  // ---- edge_hist ----
        int e = (blk - 1536) * 256 + t;
        bool is64 = (ei[1] == 0 && ei[3] == 0 && ei[5] == 0 && ei[7] == 0);
        int dst = is64 ? ei[2 * (NE + e)] : ei[NE + e];
        atomicAdd(&cnt[dst], 1);
    }
}

// ---------- persistent MFMA chain ----------
// R27 = R25 (best, 275.9us) + two isolated fixes:
//  1. conflict-free startup mapping: nl=(lane&15)+16*(t>>8),
//     kg=(lane>>4)+4*((t>>6)&3) -> per-wave LDS write addr = base+ks*128+lane
//     (linear, 0-conflict; R25's nl=t>>4 mapping was a 16-way write conflict,
//     SQ_LDS_BANK_CONFLICT 475K->2.08M, ~2.7us one-time)
//  2. feat plane store moved AFTER the drain-sync: it has no intra-kernel
//     consumer, so publish happens after draining only the 16KB frag stores;
//     the 8KB plane store flies during t0's barrier spin, drained at sync_c.
// R26 lesson pinned: LDS float atomics are ~10x slower than plain ds_write
// passes -- two-phase g1-write/g0-add reduction restored (R25-exact).
// Topology pinned (R19-R24): 32 blocks/batch, split-K, t0-only spinner.
__global__ __launch_bounds__(512) void gemm_chain(const float* __restrict__ Lap,
                                                  uint4* __restrict__ PfA,
                                                  uint4* __restrict__ PfB,
                                                  unsigned short* __restrict__ feat,
                                                  unsigned* bar) {
    extern __shared__ __align__(16) char smem[];
    uint4* ldsS = (uint4*)smem;               // 8192 uint4 = 128 KB
    float* Dl = (float*)(smem + 131072);      // 128 x 36 floats = 18.4 KB

    int b = blockIdx.x & 7, bx = blockIdx.x >> 3;   // XCD pinning
    int t = threadIdx.x;
    int w = t >> 6, lane = t & 63;
    int g = w >> 2, wq = w & 3;               // K-half, msub-pair
    int n0 = 32 * bx;

    // ---- startup: S slice (rows n0..n0+31, all k) direct from Lap -> LDS ----
    // layout: ldsS[nsubLocal*4096 + ks*128 + hl*64 + l], ks 0..31
    // frag el = S[n = 16*nsubLocal + (l&15) + n0][k = 32*ks + 8*(l>>4) + j]
    // mapping chosen so l == lane (conflict-free linear LDS writes):
    {
        int nl = (lane & 15) + 16 * (t >> 8);        // row within slice
        int kg = (lane >> 4) + 4 * ((t >> 6) & 3);   // koct low index
        const float* row = Lap + ((size_t)b * N + n0 + nl) * N;
        int base = (t >> 8) * 4096;                  // (nl>>4)*4096
        #pragma unroll
        for (int jj = 0; jj < 8; jj++) {
            int koct = kg + 16 * jj;
            int k0 = koct * 8;
            float4 f0 = *(const float4*)(row + k0);
            float4 f1 = *(const float4*)(row + k0 + 4);
            float e[8] = {f0.x, f0.y, f0.z, f0.w, f1.x, f1.y, f1.z, f1.w};
            U4 hi, lo;
            #pragma unroll
            for (int j = 0; j < 8; j++) split_bf16(e[j], hi.s[j], lo.s[j]);
            int ks = koct >> 2;                      // = (t>>6&3) + 4*jj, wave-uniform
            int l = (nl & 15) + 16 * (koct & 3);     // == lane
            ldsS[base + ks * 128 + l] = hi.v;
            ldsS[base + ks * 128 + 64 + l] = lo.v;
        }
    }
    __syncthreads();

    #pragma unroll 1
    for (int k = 0; k < KF - 1; k++) {
        const uint4* PfIn = (k & 1) ? PfB : PfA;
        uint4* PfOut      = (k & 1) ? PfA : PfB;
        const uint4* Pw0 = PfIn + (size_t)(b * 8 + 2 * wq) * 4096 + (size_t)(16 * g) * 128;
        const uint4* Pw1 = Pw0 + 4096;

        f32x4 acc[2][2] = {};                 // [mi][ni]
        uint4 ph[2][2], pl[2][2];             // [ring][mi]
        #pragma unroll
        for (int q = 0; q < 2; q++) {
            ph[q][0] = Pw0[(size_t)q * 128 + lane];
            pl[q][0] = Pw0[(size_t)q * 128 + 64 + lane];
            ph[q][1] = Pw1[(size_t)q * 128 + lane];
            pl[q][1] = Pw1[(size_t)q * 128 + 64 + lane];
        }
        #pragma unroll 2
        for (int ks = 0; ks < 16; ks++) {
            int kg = 16 * g + ks;
            uint4 a0h = ph[ks & 1][0], a0l = pl[ks & 1][0];
            uint4 a1h = ph[ks & 1][1], a1l = pl[ks & 1][1];
            if (ks < 14) {
                ph[ks & 1][0] = Pw0[(size_t)(ks + 2) * 128 + lane];
                pl[ks & 1][0] = Pw0[(size_t)(ks + 2) * 128 + 64 + lane];
                ph[ks & 1][1] = Pw1[(size_t)(ks + 2) * 128 + lane];
                pl[ks & 1][1] = Pw1[(size_t)(ks + 2) * 128 + 64 + lane];
            }
            bf16x8 b0h = __builtin_bit_cast(bf16x8, ldsS[kg * 128 + lane]);
            bf16x8 b0l = __builtin_bit_cast(bf16x8, ldsS[kg * 128 + 64 + lane]);
            bf16x8 b1h = __builtin_bit_cast(bf16x8, ldsS[4096 + kg * 128 + lane]);
            bf16x8 b1l = __builtin_bit_cast(bf16x8, ldsS[4096 + kg * 128 + 64 + lane]);
            bf16x8 A0h = __builtin_bit_cast(bf16x8, a0h);
            bf16x8 A0l = __builtin_bit_cast(bf16x8, a0l);
            bf16x8 A1h = __builtin_bit_cast(bf16x8, a1h);
            bf16x8 A1l = __builtin_bit_cast(bf16x8, a1l);
            acc[0][0] = __builtin_amdgcn_mfma_f32_16x16x32_bf16(A0h, b0h, acc[0][0], 0, 0, 0);
            acc[0][0] = __builtin_amdgcn_mfma_f32_16x16x32_bf16(A0h, b0l, acc[0][0], 0, 0, 0);
            acc[0][0] = __builtin_amdgcn_mfma_f32_16x16x32_bf16(A0l, b0h, acc[0][0], 0, 0, 0);
            acc[0][1] = __builtin_amdgcn_mfma_f32_16x16x32_bf16(A0h, b1h, acc[0][1], 0, 0, 0);
            acc[0][1] = __builtin_amdgcn_mfma_f32_16x16x32_bf16(A0h, b1l, acc[0][1], 0, 0, 0);
            acc[0][1] = __builtin_amdgcn_mfma_f32_16x16x32_bf16(A0l, b1h, acc[0][1], 0, 0, 0);
            acc[1][0] = __builtin_amdgcn_mfma_f32_16x16x32_bf16(A1h, b0h, acc[1][0], 0, 0, 0);
            acc[1][0] = __builtin_amdgcn_mfma_f32_16x16x32_bf16(A1h, b0l, acc[1][0], 0, 0, 0);
            acc[1][0] = __builtin_amdgcn_mfma_f32_16x16x32_bf16(A1l, b0h, acc[1][0], 0, 0, 0);
            acc[1][1] = __builtin_amdgcn_mfma_f32_16x16x32_bf16(A1h, b1h, acc[1][1], 0, 0, 0);
            acc[1][1] = __builtin_amdgcn_mfma_f32_16x16x32_bf16(A1h, b1l, acc[1][1], 0, 0, 0);
            acc[1][1] = __builtin_amdgcn_mfma_f32_16x16x32_bf16(A1l, b1h, acc[1][1], 0, 0, 0);
        }

        // ---- K-half reduction through Dl: g=1 writes, g=0 adds ----
        if (g == 1) {
            #pragma unroll
            for (int mi = 0; mi < 2; mi++)
                #pragma unroll
                for (int ni = 0; ni < 2; ni++)
                    #pragma unroll
                    for (int r = 0; r < 4; r++) {
                        int m = 32 * wq + 16 * mi + 4 * (lane >> 4) + r;
                        int c = 16 * ni + (lane & 15);
                        Dl[m * 36 + c] = acc[mi][ni][r];
                    }
        }
        __syncthreads();
        if (g == 0) {
            #pragma unroll
            for (int mi = 0; mi < 2; mi++)
                #pragma unroll
                for (int ni = 0; ni < 2; ni++)
                    #pragma unroll
                    for (int r = 0; r < 4; r++) {
                        int m = 32 * wq + 16 * mi + 4 * (lane >> 4) + r;
                        int c = 16 * ni + (lane & 15);
                        Dl[m * 36 + c] += acc[mi][ni][r];
                    }
        }
        __syncthreads();

        // ---- merged conversion: ONE split pass -> Pf frags; plane deferred ----
        {
            int m = t >> 2, c0 = (t & 3) * 8;   // thread covers (m, c0..c0+7)
            float4 v0 = *(const float4*)&Dl[m * 36 + c0];
            float4 v1 = *(const float4*)&Dl[m * 36 + c0 + 4];
            float e[8] = {v0.x, v0.y, v0.z, v0.w, v1.x, v1.y, v1.z, v1.w};
            U4 hi, lo;
            #pragma unroll
            for (int j = 0; j < 8; j++) split_bf16(e[j], hi.s[j], lo.s[j]);
            unsigned short* plane = feat + ((size_t)b * KF + (k + 1)) * NM
                                        + (size_t)m * N + n0 + c0;
            if (k < KF - 2) {
                int l = (m & 15) + 16 * (c0 >> 3);    // bijection onto 0..63/wave
                PfOut[PF4(b, m >> 4, bx, 0, l)] = hi.v;
                PfOut[PF4(b, m >> 4, bx, 1, l)] = lo.v;
                __syncthreads();   // sync_b: frag stores drained (vmcnt 0); Dl reads done
                if (t == 0)
                    __hip_atomic_fetch_add(&bar[b * 32], 1u, __ATOMIC_RELAXED,
                                           __HIP_MEMORY_SCOPE_AGENT);
                // plane store has NO intra-kernel consumer: issue it now so it
                // flies during the barrier spin; sync_c drains it afterward.
                *(uint4*)plane = hi.v;
                if (t == 0) {
                    unsigned target = 32u * (unsigned)(k + 1);
                    while (__hip_atomic_load(&bar[b * 32], __ATOMIC_RELAXED,
                                             __HIP_MEMORY_SCOPE_AGENT) < target)
                        __builtin_amdgcn_s_sleep(1);
                }
                __syncthreads();   // sync_c
                // invalidate this CU's vector L1 so Pf reads come from fresh L2
                asm volatile("buffer_inv sc0\n\ts_waitcnt vmcnt(0)" ::: "memory");
            } else {
                *(uint4*)plane = hi.v;        // final step: plane only
            }
        }
    }
}

// ---------- BN stats (XCD-aligned, bf16 feat) + edge CSR scan (block 0) ----------
__global__ __launch_bounds__(256) void bn_stats_scan(const unsigned short* __restrict__ feat,
                                                     const float* __restrict__ lin_w,
                                                     const float* __restrict__ lin_b,
                                                     float* __restrict__ stats,
                                                     const int* __restrict__ cnt,
                                                     int* __restrict__ off,
                                                     int* __restrict__ cur) {
    __shared__ float wls[KF * C];
    __shared__ float red[4][2][C];
    __shared__ int ss[256];
    int t = threadIdx.x;
    if (blockIdx.x < 8) {                 // ---- edge_scan (block 0 only) ----
        if (blockIdx.x == 0) {
            int base = t * 32;
            int local[32];
            int s = 0;
            #pragma unroll
            for (int i = 0; i < 32; i++) { local[i] = cnt[base + i]; s += local[i]; }
            ss[t] = s;
            __syncthreads();
            #pragma unroll
            for (int d = 1; d < 256; d <<= 1) {
                int v = (t >= d) ? ss[t - d] : 0;
                __syncthreads();
                ss[t] += v;
                __syncthreads();
            }
            int excl = ss[t] - s;
            #pragma unroll
            for (int i = 0; i < 32; i++) { off[base + i] = excl; cur[base + i] = excl; excl += local[i]; }
        }
        return;
    }
    int blk = blockIdx.x - 8;             // ---- bn_stats ----
    wls[t] = lin_w[t];
    __syncthreads();
    int b = blk & 7;
    int i = (blk >> 3) * 256 + t;          // group of 4 elems, 32768/batch
    const uint2* fb = (const uint2*)(feat + (size_t)b * KF * NM);

    float4 hacc[C];
    #pragma unroll
    for (int c = 0; c < C; c++) {
        float bb = lin_b[c];
        hacc[c] = make_float4(bb, bb, bb, bb);
    }
    for (int kk = 0; kk < KF; kk++) {
        U2 u; u.v = fb[(size_t)kk * (NM / 4) + i];
        float p0 = bf2f(u.s[0]), p1 = bf2f(u.s[1]), p2 = bf2f(u.s[2]), p3 = bf2f(u.s[3]);
        #pragma unroll
        for (int c = 0; c < C; c++) {
            float wv = wls[kk * C + c];
            hacc[c].x = fmaf(p0, wv, hacc[c].x);
            hacc[c].y = fmaf(p1, wv, hacc[c].y);
            hacc[c].z = fmaf(p2, wv, hacc[c].z);
            hacc[c].w = fmaf(p3, wv, hacc[c].w);
        }
    }
    float s[C], ssq[C];
    #pragma unroll
    for (int c = 0; c < C; c++) {
        float4 hh = hacc[c];
        s[c] = hh.x + hh.y + hh.z + hh.w;
        ssq[c] = hh.x * hh.x + hh.y * hh.y + hh.z * hh.z + hh.w * hh.w;
    }
    #pragma unroll
    for (int o = 32; o > 0; o >>= 1)
        #pragma unroll
        for (int c = 0; c < C; c++) {
            s[c] += __shfl_down(s[c], o);
            ssq[c] += __shfl_down(ssq[c], o);
        }
    if ((t & 63) == 0) {
        int wv = t >> 6;
        #pragma unroll
        for (int c = 0; c < C; c++) { red[wv][0][c] = s[c]; red[wv][1][c] = ssq[c]; }
    }
    __syncthreads();
    if (t < 32) {
        int which = t >> 4, c = t & 15;
        float v = red[0][which][c] + red[1][which][c] + red[2][which][c] + red[3][which][c];
        atomicAdd(&stats[b * 32 + which * 16 + c], v);
    }
}

// ---------- BN apply + relu + mean over M -> x | edge fill (blocks >= 256) ----------
__global__ __launch_bounds__(256) void bnx_fill(const unsigned short* __restrict__ feat,
                                                const float* __restrict__ lin_w,
                                                const float* __restrict__ lin_b,
                                                const float* __restrict__ gam,
                                                const float* __restrict__ bet,
                                                const float* __restrict__ stats,
                                                float* __restrict__ x,
                                                const int* __restrict__ ei,
                                                int* __restrict__ cur,
                                                int* __restrict__ bucket) {
    __shared__ float wls[KF * C];
    __shared__ float red[8][32 * 17];
    int t = threadIdx.x;
    if (blockIdx.x >= 256) {              // ---- edge_fill ----
        int e = (blockIdx.x - 256) * 256 + t;
        bool is64 = (ei[1] == 0 && ei[3] == 0 && ei[5] == 0 && ei[7] == 0);
        int src, dst;
        if (is64) { src = ei[2 * e]; dst = ei[2 * (NE + e)]; }
        else      { src = ei[e];     dst = ei[NE + e]; }
        int pos = atomicAdd(&cur[dst], 1);
        bucket[pos] = src;
        return;
    }
    // ---- bn_x ----
    wls[t] = lin_w[t];
    __syncthreads();
    int grp = blockIdx.x;
    int b = grp & 7, n0 = (grp >> 3) * 32;
    int nl = t & 31, mg = t >> 5;
    int n = n0 + nl;

    const float inv_nm = 1.0f / (float)NM;
    float sc[C], sh[C], bb[C];
    #pragma unroll
    for (int c = 0; c < C; c++) {
        float mean = stats[b * 32 + c] * inv_nm;
        float var = stats[b * 32 + 16 + c] * inv_nm - mean * mean;
        sc[c] = gam[c] * rsqrtf(var + BN_EPS);
        sh[c] = bet[c] - mean * sc[c];
        bb[c] = lin_b[c];
    }
    const unsigned short* fb = feat + (size_t)b * KF * NM + n;
    float y[C] = {};
    for (int m = mg * 16; m < mg * 16 + 16; m++) {
        float p[KF];
        #pragma unroll
        for (int kk = 0; kk < KF; kk++) p[kk] = bf2f(fb[(size_t)kk * NM + (size_t)m * N]);
        #pragma unroll
        for (int c = 0; c < C; c++) {
            float hh = bb[c];
            #pragma unroll
            for (int kk = 0; kk < KF; kk++) hh = fmaf(p[kk], wls[kk * C + c], hh);
            y[c] += fmaxf(fmaf(hh, sc[c], sh[c]), 0.0f);
        }
    }
    #pragma unroll
    for (int c = 0; c < C; c++) red[mg][nl * 17 + c] = y[c];
    __syncthreads();
    #pragma unroll
    for (int q = 0; q < 2; q++) {
        int slot = t + q * 256;
        int snl = slot >> 4, c = slot & 15;
        float v = 0.0f;
        #pragma unroll
        for (int m8 = 0; m8 < 8; m8++) v += red[m8][snl * 17 + c];
        v *= (1.0f / (float)M);
        x[((size_t)b * N + n0 + snl) * C + c] = v;
    }
}

// ---------- fused gather + phi1 + phi2 ----------
__global__ __launch_bounds__(256) void phi_fused(const int* __restrict__ cnt,
                                                 const int* __restrict__ off,
                                                 const int* __restrict__ bucket,
                                                 const float* __restrict__ x,
                                                 const float* __restrict__ w1,
                                                 const float* __restrict__ b1,
                                                 const float* __restrict__ w2,
                                                 const float* __restrict__ b2,
                                                 float* __restrict__ out) {
    __shared__ float w1s[C * DPE];
    __shared__ float w2s[DPE * DPE];
    __shared__ float b2s[DPE];
    __shared__ float gsh[16][17];
    __shared__ float h1sh[16][DPE];
    int t = threadIdx.x;
    #pragma unroll
    for (int q = 0; q < 4; q++) w1s[t + q * 256] = w1[t + q * 256];
    #pragma unroll
    for (int q = 0; q < 16; q++) w2s[t + q * 256] = w2[t + q * 256];
    if (t < DPE) b2s[t] = b2[t];

    {   // gather: node nl, channel c
        int nl = t >> 4, c = t & 15;
        int n = blockIdx.x * 16 + nl;
        int o = off[n], d = cnt[n];
        float v = x[(size_t)n * C + c];
        int j = 0;
        for (; j + 4 <= d; j += 4) {
            int s0 = bucket[o + j], s1 = bucket[o + j + 1];
            int s2 = bucket[o + j + 2], s3 = bucket[o + j + 3];
            v += x[(size_t)s0 * C + c];
            v += x[(size_t)s1 * C + c];
            v += x[(size_t)s2 * C + c];
            v += x[(size_t)s3 * C + c];
        }
        for (; j < d; j++) v += x[(size_t)bucket[o + j] * C + c];
        gsh[nl][c] = v;
    }
    __syncthreads();
    #pragma unroll
    for (int q = 0; q < 4; q++) {       // phi1: 16 nodes x 64
        int item = t + 256 * q;
        int node = item >> 6, j = item & 63;
        float h = b1[j];
        #pragma unroll
        for (int c = 0; c < C; c++) h = fmaf(gsh[node][c], w1s[c * DPE + j], h);
        h1sh[node][j] = fmaxf(h, 0.0f);
    }
    __syncthreads();
    #pragma unroll
    for (int q = 0; q < 4; q++) {       // phi2: 16 nodes x 64
        int item = t + 256 * q;
        int node = item >> 6, d = item & 63;
        float o2 = b2s[d];
        #pragma unroll
        for (int j = 0; j < DPE; j++) o2 = fmaf(h1sh[node][j], w2s[j * DPE + d], o2);
        out[((size_t)blockIdx.x * 16 + node) * DPE + d] = o2;
    }
}

extern "C" void kernel_launch(void* const* d_in, const int* in_sizes, int n_in,
                              void* d_out, int out_size, void* d_ws, size_t ws_size,
                              hipStream_t stream) {
    const float* Lap   = (const float*)d_in[0];
    const float* W     = (const float*)d_in[1];
    const float* lin_w = (const float*)d_in[2];
    const float* lin_b = (const float*)d_in[3];
    const float* gam   = (const float*)d_in[4];
    const float* bet   = (const float*)d_in[5];
    const float* w1    = (const float*)d_in[6];
    const float* b1    = (const float*)d_in[7];
    const float* w2    = (const float*)d_in[8];
    const float* b2    = (const float*)d_in[9];
    const int*   ei    = (const int*)d_in[10];

    char* wsb = (char*)d_ws;
    unsigned short* feat = (unsigned short*)wsb;             // 32 MB (bf16)
    uint4* Pf    = (uint4*)(wsb + ((size_t)32 << 20));       // 8 MB (2 buffers)
    char* tail   = wsb + ((size_t)40 << 20);
    float* stats = (float*)tail;                             // 1 KB
    unsigned* bar = (unsigned*)(tail + 1024);                // 8 counters, 128B apart
    int* cnt     = (int*)(tail + 8192);                      // NV ints (32 KB)
    float* x     = (float*)(tail + 40960);
    int* off     = (int*)(x + (size_t)NV * C);
    int* cur     = off + NV;
    int* bucket  = cur + NV;                                 // NE ints
    float* out   = (float*)d_out;

    // allow 146 KB dynamic LDS (default cap is 64 KB); idempotent host-side call
    static bool attr_set = false;
    if (!attr_set) {
        hipFuncSetAttribute((const void*)gemm_chain,
                            hipFuncAttributeMaxDynamicSharedMemorySize, 149504);
        attr_set = true;
    }

    // one memset covers stats + bar + cnt (contiguous 40 KB)
    hipMemsetAsync(tail, 0, 40960, stream);
    prep_all<<<dim3(2048), 256, 0, stream>>>(W, ei, Pf, feat, cnt);
    gemm_chain<<<dim3(256), 512, 149504, stream>>>(Lap, Pf, Pf + PFBUF, feat, bar);
    bn_stats_scan<<<dim3(1032), 256, 0, stream>>>(feat, lin_w, lin_b, stats, cnt, off, cur);
    bnx_fill<<<dim3(768), 256, 0, stream>>>(feat, lin_w, lin_b, gam, bet, stats, x, ei, cur, bucket);
    phi_fused<<<dim3(NV / 16), 256, 0, stream>>>(cnt, off, bucket, x, w1, b1, w2, b2, out);
}

// Round 10
// 270.887 us; speedup vs baseline: 1.5860x; 1.0403x over previous
//
#include <hip/hip_runtime.h>

#define B 8
#define N 1024
#define M 128
#define KF 16
#define C 16
#define DPE 64
#define NE 131072
#define NV (B*N)
#define NM (N*M)
#define BN_EPS 1e-5f

typedef short bf16x8 __attribute__((ext_vector_type(8)));
typedef float f32x4 __attribute__((ext_vector_type(4)));

__device__ inline unsigned short f2bf_rne(float f) {
    unsigned u = __float_as_uint(f);
    u += 0x7fffu + ((u >> 16) & 1u);
    return (unsigned short)(u >> 16);
}
__device__ inline float bf2f(unsigned short s) {
    return __uint_as_float((unsigned)s << 16);
}
__device__ inline void split_bf16(float v, unsigned short& hi, unsigned short& lo) {
    hi = f2bf_rne(v);
    float hf = __uint_as_float((unsigned)hi << 16);
    lo = f2bf_rne(v - hf);
}
union U4 { uint4 v; unsigned short s[8]; };
union U2 { uint2 v; unsigned short s[4]; };

// Pf frag-major (uint4 units) per buffer: PF4(b,msub,ks,hl,l)
// frag el: m = 16*msub + (l&15), kcol = 32*ks + 8*(l>>4) + j
__device__ __host__ inline size_t PF4(int b, int msub, int ks, int hl, int l) {
    return ((((size_t)b * 8 + msub) * 32 + ks) * 2 + hl) * 64 + l;
}
#define PFBUF ((size_t)B * 8 * 32 * 2 * 64)   // uint4 per Pf buffer (4MB)

// ---------- fused prep: W plane0 + W-frags (merged, one W read) | edge hist ----------
// R28: prep_w_frag folded into prep_w_plane -- the T[32][33] tile of block
// (nt,mt) contains exactly frag units (ks=nt, msub in {2mt,2mt+1}); emit
// them from LDS instead of re-reading W with 8 scalar stride-512B loads.
__global__ __launch_bounds__(256) void prep_all(const float* __restrict__ W,
                                                const int* __restrict__ ei,
                                                uint4* __restrict__ Pf,
                                                unsigned short* __restrict__ feat,
                                                int* __restrict__ cnt) {
    __shared__ float T[32][33];
    int blk = blockIdx.x;
    int t = threadIdx.x;
    if (blk < 1024) {                         // ---- plane0 + frags ----
        int b = blk & 7;
        int tile = blk >> 3;
        int nt = tile & 31, mt = tile >> 5;
        int n0 = nt * 32, m0 = mt * 32;
        {
            int nl = t >> 3, mq = t & 7;
            float4 v = *(const float4*)(W + ((size_t)b * N + n0 + nl) * M + m0 + mq * 4);
            T[nl][mq * 4 + 0] = v.x; T[nl][mq * 4 + 1] = v.y;
            T[nl][mq * 4 + 2] = v.z; T[nl][mq * 4 + 3] = v.w;
        }
        __syncthreads();
        {   // plane 0 (bf16, [m][node])
            int ml = t >> 3, nq = t & 7;
            U2 o;
            o.s[0] = f2bf_rne(T[nq * 4 + 0][ml]);
            o.s[1] = f2bf_rne(T[nq * 4 + 1][ml]);
            o.s[2] = f2bf_rne(T[nq * 4 + 2][ml]);
            o.s[3] = f2bf_rne(T[nq * 4 + 3][ml]);
            unsigned short* plane = feat + (size_t)b * KF * NM;  // plane 0
            *(uint2*)(plane + (size_t)(m0 + ml) * N + n0 + nq * 4) = o.v;
        }
        if (t < 128) {  // frags for (ks=nt, msub=2mt+unit) from T
            int unit = t >> 6, l = t & 63;
            int msub = 2 * mt + unit;
            U4 hi, lo;
            #pragma unroll
            for (int j = 0; j < 8; j++) {
                float v = T[8 * (l >> 4) + j][16 * unit + (l & 15)];
                split_bf16(v, hi.s[j], lo.s[j]);
            }
            Pf[PF4(b, msub, nt, 0, l)] = hi.v;
            Pf[PF4(b, msub, nt, 1, l)] = lo.v;
        }
    } else {                                  // ---- edge_hist ----
        int e = (blk - 1024) * 256 + t;
        bool is64 = (ei[1] == 0 && ei[3] == 0 && ei[5] == 0 && ei[7] == 0);
        int dst = is64 ? ei[2 * (NE + e)] : ei[NE + e];
        atomicAdd(&cnt[dst], 1);
    }
}

// ---------- persistent MFMA chain ----------
// R28 gemm = R25 epilogue order (plane store BEFORE sync_b -- R27's deferral
// was neutral-to-negative) + R27's conflict-free startup mapping (counter-
// verified: SQ_LDS_BANK_CONFLICT 2.08M -> 245K).
// Pinned lessons: LDS float atomics ~10x slower than plain passes (R26);
// 32 blocks/batch, split-K, t0-only spinner uniquely optimal (R19-R24).
__global__ __launch_bounds__(512) void gemm_chain(const float* __restrict__ Lap,
                                                  uint4* __restrict__ PfA,
                                                  uint4* __restrict__ PfB,
                                                  unsigned short* __restrict__ feat,
                                                  unsigned* bar) {
    extern __shared__ __align__(16) char smem[];
    uint4* ldsS = (uint4*)smem;               // 8192 uint4 = 128 KB
    float* Dl = (float*)(smem + 131072);      // 128 x 36 floats = 18.4 KB

    int b = blockIdx.x & 7, bx = blockIdx.x >> 3;   // XCD pinning
    int t = threadIdx.x;
    int w = t >> 6, lane = t & 63;
    int g = w >> 2, wq = w & 3;               // K-half, msub-pair
    int n0 = 32 * bx;

    // ---- startup: S slice direct from Lap -> LDS, conflict-free mapping ----
    // layout: ldsS[nsubLocal*4096 + ks*128 + hl*64 + l], ks 0..31
    // frag el = S[n = 16*nsubLocal + (l&15) + n0][k = 32*ks + 8*(l>>4) + j]
    {
        int nl = (lane & 15) + 16 * (t >> 8);        // row within slice
        int kg = (lane >> 4) + 4 * ((t >> 6) & 3);   // koct low index
        const float* row = Lap + ((size_t)b * N + n0 + nl) * N;
        int base = (t >> 8) * 4096;                  // (nl>>4)*4096
        #pragma unroll
        for (int jj = 0; jj < 8; jj++) {
            int koct = kg + 16 * jj;
            int k0 = koct * 8;
            float4 f0 = *(const float4*)(row + k0);
            float4 f1 = *(const float4*)(row + k0 + 4);
            float e[8] = {f0.x, f0.y, f0.z, f0.w, f1.x, f1.y, f1.z, f1.w};
            U4 hi, lo;
            #pragma unroll
            for (int j = 0; j < 8; j++) split_bf16(e[j], hi.s[j], lo.s[j]);
            int ks = koct >> 2;                      // wave-uniform
            int l = (nl & 15) + 16 * (koct & 3);     // == lane
            ldsS[base + ks * 128 + l] = hi.v;
            ldsS[base + ks * 128 + 64 + l] = lo.v;
        }
    }
    __syncthreads();

    #pragma unroll 1
    for (int k = 0; k < KF - 1; k++) {
        const uint4* PfIn = (k & 1) ? PfB : PfA;
        uint4* PfOut      = (k & 1) ? PfA : PfB;
        const uint4* Pw0 = PfIn + (size_t)(b * 8 + 2 * wq) * 4096 + (size_t)(16 * g) * 128;
        const uint4* Pw1 = Pw0 + 4096;

        f32x4 acc[2][2] = {};                 // [mi][ni]
        uint4 ph[2][2], pl[2][2];             // [ring][mi]
        #pragma unroll
        for (int q = 0; q < 2; q++) {
            ph[q][0] = Pw0[(size_t)q * 128 + lane];
            pl[q][0] = Pw0[(size_t)q * 128 + 64 + lane];
            ph[q][1] = Pw1[(size_t)q * 128 + lane];
            pl[q][1] = Pw1[(size_t)q * 128 + 64 + lane];
        }
        #pragma unroll 2
        for (int ks = 0; ks < 16; ks++) {
            int kg = 16 * g + ks;
            uint4 a0h = ph[ks & 1][0], a0l = pl[ks & 1][0];
            uint4 a1h = ph[ks & 1][1], a1l = pl[ks & 1][1];
            if (ks < 14) {
                ph[ks & 1][0] = Pw0[(size_t)(ks + 2) * 128 + lane];
                pl[ks & 1][0] = Pw0[(size_t)(ks + 2) * 128 + 64 + lane];
                ph[ks & 1][1] = Pw1[(size_t)(ks + 2) * 128 + lane];
                pl[ks & 1][1] = Pw1[(size_t)(ks + 2) * 128 + 64 + lane];
            }
            bf16x8 b0h = __builtin_bit_cast(bf16x8, ldsS[kg * 128 + lane]);
            bf16x8 b0l = __builtin_bit_cast(bf16x8, ldsS[kg * 128 + 64 + lane]);
            bf16x8 b1h = __builtin_bit_cast(bf16x8, ldsS[4096 + kg * 128 + lane]);
            bf16x8 b1l = __builtin_bit_cast(bf16x8, ldsS[4096 + kg * 128 + 64 + lane]);
            bf16x8 A0h = __builtin_bit_cast(bf16x8, a0h);
            bf16x8 A0l = __builtin_bit_cast(bf16x8, a0l);
            bf16x8 A1h = __builtin_bit_cast(bf16x8, a1h);
            bf16x8 A1l = __builtin_bit_cast(bf16x8, a1l);
            acc[0][0] = __builtin_amdgcn_mfma_f32_16x16x32_bf16(A0h, b0h, acc[0][0], 0, 0, 0);
            acc[0][0] = __builtin_amdgcn_mfma_f32_16x16x32_bf16(A0h, b0l, acc[0][0], 0, 0, 0);
            acc[0][0] = __builtin_amdgcn_mfma_f32_16x16x32_bf16(A0l, b0h, acc[0][0], 0, 0, 0);
            acc[0][1] = __builtin_amdgcn_mfma_f32_16x16x32_bf16(A0h, b1h, acc[0][1], 0, 0, 0);
            acc[0][1] = __builtin_amdgcn_mfma_f32_16x16x32_bf16(A0h, b1l, acc[0][1], 0, 0, 0);
            acc[0][1] = __builtin_amdgcn_mfma_f32_16x16x32_bf16(A0l, b1h, acc[0][1], 0, 0, 0);
            acc[1][0] = __builtin_amdgcn_mfma_f32_16x16x32_bf16(A1h, b0h, acc[1][0], 0, 0, 0);
            acc[1][0] = __builtin_amdgcn_mfma_f32_16x16x32_bf16(A1h, b0l, acc[1][0], 0, 0, 0);
            acc[1][0] = __builtin_amdgcn_mfma_f32_16x16x32_bf16(A1l, b0h, acc[1][0], 0, 0, 0);
            acc[1][1] = __builtin_amdgcn_mfma_f32_16x16x32_bf16(A1h, b1h, acc[1][1], 0, 0, 0);
            acc[1][1] = __builtin_amdgcn_mfma_f32_16x16x32_bf16(A1h, b1l, acc[1][1], 0, 0, 0);
            acc[1][1] = __builtin_amdgcn_mfma_f32_16x16x32_bf16(A1l, b1h, acc[1][1], 0, 0, 0);
        }

        // ---- K-half reduction through Dl: g=1 writes, g=0 adds ----
        if (g == 1) {
            #pragma unroll
            for (int mi = 0; mi < 2; mi++)
                #pragma unroll
                for (int ni = 0; ni < 2; ni++)
                    #pragma unroll
                    for (int r = 0; r < 4; r++) {
                        int m = 32 * wq + 16 * mi + 4 * (lane >> 4) + r;
                        int c = 16 * ni + (lane & 15);
                        Dl[m * 36 + c] = acc[mi][ni][r];
                    }
        }
        __syncthreads();
        if (g == 0) {
            #pragma unroll
            for (int mi = 0; mi < 2; mi++)
                #pragma unroll
                for (int ni = 0; ni < 2; ni++)
                    #pragma unroll
                    for (int r = 0; r < 4; r++) {
                        int m = 32 * wq + 16 * mi + 4 * (lane >> 4) + r;
                        int c = 16 * ni + (lane & 15);
                        Dl[m * 36 + c] += acc[mi][ni][r];
                    }
        }
        __syncthreads();

        // ---- merged conversion: ONE split pass -> feat plane + Pf frags ----
        {
            int m = t >> 2, c0 = (t & 3) * 8;   // thread covers (m, c0..c0+7)
            float4 v0 = *(const float4*)&Dl[m * 36 + c0];
            float4 v1 = *(const float4*)&Dl[m * 36 + c0 + 4];
            float e[8] = {v0.x, v0.y, v0.z, v0.w, v1.x, v1.y, v1.z, v1.w};
            U4 hi, lo;
            #pragma unroll
            for (int j = 0; j < 8; j++) split_bf16(e[j], hi.s[j], lo.s[j]);
            unsigned short* plane = feat + ((size_t)b * KF + (k + 1)) * NM
                                        + (size_t)m * N + n0 + c0;
            *(uint4*)plane = hi.v;
            if (k < KF - 2) {
                int l = (m & 15) + 16 * (c0 >> 3);    // bijection onto 0..63/wave
                PfOut[PF4(b, m >> 4, bx, 0, l)] = hi.v;
                PfOut[PF4(b, m >> 4, bx, 1, l)] = lo.v;
            }
        }
        if (k < KF - 2) {
            __syncthreads();   // drains all waves' stores to L2 (vmcnt 0)
            if (t == 0) {
                __hip_atomic_fetch_add(&bar[b * 32], 1u, __ATOMIC_RELAXED,
                                       __HIP_MEMORY_SCOPE_AGENT);
                unsigned target = 32u * (unsigned)(k + 1);
                while (__hip_atomic_load(&bar[b * 32], __ATOMIC_RELAXED,
                                         __HIP_MEMORY_SCOPE_AGENT) < target)
                    __builtin_amdgcn_s_sleep(1);
            }
            __syncthreads();
            // invalidate this CU's vector L1 so Pf reads come from fresh L2
            asm volatile("buffer_inv sc0\n\ts_waitcnt vmcnt(0)" ::: "memory");
        }
    }
}

// ---------- BN stats (XCD-aligned, bf16 feat) + edge CSR scan (block 0) ----------
__global__ __launch_bounds__(256) void bn_stats_scan(const unsigned short* __restrict__ feat,
                                                     const float* __restrict__ lin_w,
                                                     const float* __restrict__ lin_b,
                                                     float* __restrict__ stats,
                                                     const int* __restrict__ cnt,
                                                     int* __restrict__ off,
                                                     int* __restrict__ cur) {
    __shared__ float wls[KF * C];
    __shared__ float red[4][2][C];
    __shared__ int ss[256];
    int t = threadIdx.x;
    if (blockIdx.x < 8) {                 // ---- edge_scan (block 0 only) ----
        if (blockIdx.x == 0) {
            int base = t * 32;
            int local[32];
            int s = 0;
            #pragma unroll
            for (int i = 0; i < 32; i++) { local[i] = cnt[base + i]; s += local[i]; }
            ss[t] = s;
            __syncthreads();
            #pragma unroll
            for (int d = 1; d < 256; d <<= 1) {
                int v = (t >= d) ? ss[t - d] : 0;
                __syncthreads();
                ss[t] += v;
                __syncthreads();
            }
            int excl = ss[t] - s;
            #pragma unroll
            for (int i = 0; i < 32; i++) { off[base + i] = excl; cur[base + i] = excl; excl += local[i]; }
        }
        return;
    }
    int blk = blockIdx.x - 8;             // ---- bn_stats ----
    wls[t] = lin_w[t];
    __syncthreads();
    int b = blk & 7;
    int i = (blk >> 3) * 256 + t;          // group of 4 elems, 32768/batch
    const uint2* fb = (const uint2*)(feat + (size_t)b * KF * NM);

    float4 hacc[C];
    #pragma unroll
    for (int c = 0; c < C; c++) {
        float bb = lin_b[c];
        hacc[c] = make_float4(bb, bb, bb, bb);
    }
    for (int kk = 0; kk < KF; kk++) {
        U2 u; u.v = fb[(size_t)kk * (NM / 4) + i];
        float p0 = bf2f(u.s[0]), p1 = bf2f(u.s[1]), p2 = bf2f(u.s[2]), p3 = bf2f(u.s[3]);
        #pragma unroll
        for (int c = 0; c < C; c++) {
            float wv = wls[kk * C + c];
            hacc[c].x = fmaf(p0, wv, hacc[c].x);
            hacc[c].y = fmaf(p1, wv, hacc[c].y);
            hacc[c].z = fmaf(p2, wv, hacc[c].z);
            hacc[c].w = fmaf(p3, wv, hacc[c].w);
        }
    }
    float s[C], ssq[C];
    #pragma unroll
    for (int c = 0; c < C; c++) {
        float4 hh = hacc[c];
        s[c] = hh.x + hh.y + hh.z + hh.w;
        ssq[c] = hh.x * hh.x + hh.y * hh.y + hh.z * hh.z + hh.w * hh.w;
    }
    #pragma unroll
    for (int o = 32; o > 0; o >>= 1)
        #pragma unroll
        for (int c = 0; c < C; c++) {
            s[c] += __shfl_down(s[c], o);
            ssq[c] += __shfl_down(ssq[c], o);
        }
    if ((t & 63) == 0) {
        int wv = t >> 6;
        #pragma unroll
        for (int c = 0; c < C; c++) { red[wv][0][c] = s[c]; red[wv][1][c] = ssq[c]; }
    }
    __syncthreads();
    if (t < 32) {
        int which = t >> 4, c = t & 15;
        float v = red[0][which][c] + red[1][which][c] + red[2][which][c] + red[3][which][c];
        atomicAdd(&stats[b * 32 + which * 16 + c], v);
    }
}

// ---------- BN apply + relu + mean over M -> x | edge fill (blocks >= 256) ----------
__global__ __launch_bounds__(256) void bnx_fill(const unsigned short* __restrict__ feat,
                                                const float* __restrict__ lin_w,
                                                const float* __restrict__ lin_b,
                                                const float* __restrict__ gam,
                                                const float* __restrict__ bet,
                                                const float* __restrict__ stats,
                                                float* __restrict__ x,
                                                const int* __restrict__ ei,
                                                int* __restrict__ cur,
                                                int* __restrict__ bucket) {
    __shared__ float wls[KF * C];
    __shared__ float red[8][32 * 17];
    int t = threadIdx.x;
    if (blockIdx.x >= 256) {              // ---- edge_fill ----
        int e = (blockIdx.x - 256) * 256 + t;
        bool is64 = (ei[1] == 0 && ei[3] == 0 && ei[5] == 0 && ei[7] == 0);
        int src, dst;
        if (is64) { src = ei[2 * e]; dst = ei[2 * (NE + e)]; }
        else      { src = ei[e];     dst = ei[NE + e]; }
        int pos = atomicAdd(&cur[dst], 1);
        bucket[pos] = src;
        return;
    }
    // ---- bn_x ----
    wls[t] = lin_w[t];
    __syncthreads();
    int grp = blockIdx.x;
    int b = grp & 7, n0 = (grp >> 3) * 32;
    int nl = t & 31, mg = t >> 5;
    int n = n0 + nl;

    const float inv_nm = 1.0f / (float)NM;
    float sc[C], sh[C], bb[C];
    #pragma unroll
    for (int c = 0; c < C; c++) {
        float mean = stats[b * 32 + c] * inv_nm;
        float var = stats[b * 32 + 16 + c] * inv_nm - mean * mean;
        sc[c] = gam[c] * rsqrtf(var + BN_EPS);
        sh[c] = bet[c] - mean * sc[c];
        bb[c] = lin_b[c];
    }
    const unsigned short* fb = feat + (size_t)b * KF * NM + n;
    float y[C] = {};
    for (int m = mg * 16; m < mg * 16 + 16; m++) {
        float p[KF];
        #pragma unroll
        for (int kk = 0; kk < KF; kk++) p[kk] = bf2f(fb[(size_t)kk * NM + (size_t)m * N]);
        #pragma unroll
        for (int c = 0; c < C; c++) {
            float hh = bb[c];
            #pragma unroll
            for (int kk = 0; kk < KF; kk++) hh = fmaf(p[kk], wls[kk * C + c], hh);
            y[c] += fmaxf(fmaf(hh, sc[c], sh[c]), 0.0f);
        }
    }
    #pragma unroll
    for (int c = 0; c < C; c++) red[mg][nl * 17 + c] = y[c];
    __syncthreads();
    #pragma unroll
    for (int q = 0; q < 2; q++) {
        int slot = t + q * 256;
        int snl = slot >> 4, c = slot & 15;
        float v = 0.0f;
        #pragma unroll
        for (int m8 = 0; m8 < 8; m8++) v += red[m8][snl * 17 + c];
        v *= (1.0f / (float)M);
        x[((size_t)b * N + n0 + snl) * C + c] = v;
    }
}

// ---------- fused gather + phi1 + phi2 ----------
__global__ __launch_bounds__(256) void phi_fused(const int* __restrict__ cnt,
                                                 const int* __restrict__ off,
                                                 const int* __restrict__ bucket,
                                                 const float* __restrict__ x,
                                                 const float* __restrict__ w1,
                                                 const float* __restrict__ b1,
                                                 const float* __restrict__ w2,
                                                 const float* __restrict__ b2,
                                                 float* __restrict__ out) {
    __shared__ float w1s[C * DPE];
    __shared__ float w2s[DPE * DPE];
    __shared__ float b2s[DPE];
    __shared__ float gsh[16][17];
    __shared__ float h1sh[16][DPE];
    int t = threadIdx.x;
    #pragma unroll
    for (int q = 0; q < 4; q++) w1s[t + q * 256] = w1[t + q * 256];
    #pragma unroll
    for (int q = 0; q < 16; q++) w2s[t + q * 256] = w2[t + q * 256];
    if (t < DPE) b2s[t] = b2[t];

    {   // gather: node nl, channel c
        int nl = t >> 4, c = t & 15;
        int n = blockIdx.x * 16 + nl;
        int o = off[n], d = cnt[n];
        float v = x[(size_t)n * C + c];
        int j = 0;
        for (; j + 4 <= d; j += 4) {
            int s0 = bucket[o + j], s1 = bucket[o + j + 1];
            int s2 = bucket[o + j + 2], s3 = bucket[o + j + 3];
            v += x[(size_t)s0 * C + c];
            v += x[(size_t)s1 * C + c];
            v += x[(size_t)s2 * C + c];
            v += x[(size_t)s3 * C + c];
        }
        for (; j < d; j++) v += x[(size_t)bucket[o + j] * C + c];
        gsh[nl][c] = v;
    }
    __syncthreads();
    #pragma unroll
    for (int q = 0; q < 4; q++) {       // phi1: 16 nodes x 64
        int item = t + 256 * q;
        int node = item >> 6, j = item & 63;
        float h = b1[j];
        #pragma unroll
        for (int c = 0; c < C; c++) h = fmaf(gsh[node][c], w1s[c * DPE + j], h);
        h1sh[node][j] = fmaxf(h, 0.0f);
    }
    __syncthreads();
    #pragma unroll
    for (int q = 0; q < 4; q++) {       // phi2: 16 nodes x 64
        int item = t + 256 * q;
        int node = item >> 6, d = item & 63;
        float o2 = b2s[d];
        #pragma unroll
        for (int j = 0; j < DPE; j++) o2 = fmaf(h1sh[node][j], w2s[j * DPE + d], o2);
        out[((size_t)blockIdx.x * 16 + node) * DPE + d] = o2;
    }
}

extern "C" void kernel_launch(void* const* d_in, const int* in_sizes, int n_in,
                              void* d_out, int out_size, void* d_ws, size_t ws_size,
                              hipStream_t stream) {
    const float* Lap   = (const float*)d_in[0];
    const float* W     = (const float*)d_in[1];
    const float* lin_w = (const float*)d_in[2];
    const float* lin_b = (const float*)d_in[3];
    const float* gam   = (const float*)d_in[4];
    const float* bet   = (const float*)d_in[5];
    const float* w1    = (const float*)d_in[6];
    const float* b1    = (const float*)d_in[7];
    const float* w2    = (const float*)d_in[8];
    const float* b2    = (const float*)d_in[9];
    const int*   ei    = (const int*)d_in[10];

    char* wsb = (char*)d_ws;
    unsigned short* feat = (unsigned short*)wsb;             // 32 MB (bf16)
    uint4* Pf    = (uint4*)(wsb + ((size_t)32 << 20));       // 8 MB (2 buffers)
    char* tail   = wsb + ((size_t)40 << 20);
    float* stats = (float*)tail;                             // 1 KB
    unsigned* bar = (unsigned*)(tail + 1024);                // 8 counters, 128B apart
    int* cnt     = (int*)(tail + 8192);                      // NV ints (32 KB)
    float* x     = (float*)(tail + 40960);
    int* off     = (int*)(x + (size_t)NV * C);
    int* cur     = off + NV;
    int* bucket  = cur + NV;                                 // NE ints
    float* out   = (float*)d_out;

    // allow 146 KB dynamic LDS (default cap is 64 KB); idempotent host-side call
    static bool attr_set = false;
    if (!attr_set) {
        hipFuncSetAttribute((const void*)gemm_chain,
                            hipFuncAttributeMaxDynamicSharedMemorySize, 149504);
        attr_set = true;
    }

    // one memset covers stats + bar + cnt (contiguous 40 KB)
    hipMemsetAsync(tail, 0, 40960, stream);
    prep_all<<<dim3(1536), 256, 0, stream>>>(W, ei, Pf, feat, cnt);
    gemm_chain<<<dim3(256), 512, 149504, stream>>>(Lap, Pf, Pf + PFBUF, feat, bar);
    bn_stats_scan<<<dim3(1032), 256, 0, stream>>>(feat, lin_w, lin_b, stats, cnt, off, cur);
    bnx_fill<<<dim3(768), 256, 0, stream>>>(feat, lin_w, lin_b, gam, bet, stats, x, ei, cur, bucket);
    phi_fused<<<dim3(NV / 16), 256, 0, stream>>>(cnt, off, bucket, x, w1, b1, w2, b2, out);
}